// Round 1
// baseline (208.887 us; speedup 1.0000x reference)
//
#include <hip/hip_runtime.h>

#define NB_BITS     11
#define N_BUCKETS   (1 << NB_BITS)            // 2048 buckets (top 11 key bits)
#define LOCAL_BITS  18                        // low 18 bits -> 8192-word bitmap
#define LOCAL_WORDS 8192                      // 32 KB
#define LKMASK      ((1u << LOCAL_BITS) - 1u)
#define KEYMASK     0x1FFFFFFFu
#define NXCD        8
#define WCAP        512                       // per-(bucket,xcd) window cap: mean 248, +16.8 sigma
#define WSHIFT      9                         // log2(WCAP)
#define FE_CAP      2560                      // unique/bucket: mean 1946, +13 sigma
#define PPT         16                        // points per thread per tile
#define TILE        (1024 * PPT)              // 16384 points per block

__device__ __forceinline__ unsigned make_key(int4 c) {
    return ((((unsigned)c.x << 7) | (unsigned)(c.y >> 1)) << 7 | (unsigned)(c.z >> 1)) << 7
         | (unsigned)(c.w >> 1);
}

// exclusive block scan over NW waves; 2 internal barriers
template<int NW>
__device__ inline void block_scan(unsigned v, unsigned* wsum, unsigned& excl, unsigned& total) {
    int t = threadIdx.x, ln = t & 63, wv = t >> 6;
    unsigned incl = v;
    #pragma unroll
    for (int off = 1; off < 64; off <<= 1) {
        unsigned y = __shfl_up(incl, off, 64);
        if (ln >= off) incl += y;
    }
    if (ln == 63) wsum[wv] = incl;
    __syncthreads();
    if (wv == 0) {
        unsigned s = (ln < NW) ? wsum[ln] : 0u;
        #pragma unroll
        for (int off = 1; off < NW; off <<= 1) {
            unsigned y = __shfl_up(s, off, 64);
            if (ln >= off) s += y;
        }
        if (ln < NW) wsum[ln] = s;
    }
    __syncthreads();
    excl = (wv ? wsum[wv - 1] : 0u) + incl - v;
    total = wsum[NW - 1];
}

// ---- pass 1: fused key-build + LDS-hist rank + global reserve + scatter ----
// Replaces hist/offs/scatter: rank comes from ONE LDS atomicAdd (returns old),
// per-tile ranges reserved via global cursors. Sub-window per blockIdx&7 keeps
// adjacent reservations on the same XCD (L2 line aggregation for 4B writes).
__global__ void __launch_bounds__(1024, 4)
build_pass(const int4* __restrict__ coords,
           unsigned* __restrict__ gcur,     // [N_BUCKETS][NXCD] cursors->counts
           unsigned* __restrict__ pairs,    // [N_BUCKETS][NXCD][WCAP]
           int n) {
    __shared__ unsigned h[N_BUCKETS];        // 8 KB: counts, then bases
    int t = threadIdx.x, blk = blockIdx.x;
    unsigned xcd = (unsigned)blk & 7u;
    int base = blk * TILE;
    unsigned skey[PPT], lrank[PPT];
    h[t] = 0u; h[t + 1024] = 0u;
    #pragma unroll
    for (int m = 0; m < PPT; ++m) {
        int i = base + t + m * 1024;
        if (i < n) {
            int4 c = coords[i];
            unsigned key = make_key(c);
            unsigned pos = (unsigned)((c.y & 1) | ((c.z & 1) << 1) | ((c.w & 1) << 2));
            skey[m] = (pos << 29) | key;
        }
    }
    __syncthreads();
    #pragma unroll
    for (int m = 0; m < PPT; ++m) {
        int i = base + t + m * 1024;
        if (i < n)
            lrank[m] = atomicAdd(&h[(skey[m] & KEYMASK) >> LOCAL_BITS], 1u);
    }
    __syncthreads();
    #pragma unroll
    for (int q = 0; q < 2; ++q) {
        int j = t + q * 1024;
        unsigned c = h[j];
        if (c) h[j] = atomicAdd(&gcur[((unsigned)j << 3) | xcd], c);  // count -> base
    }
    __syncthreads();
    #pragma unroll
    for (int m = 0; m < PPT; ++m) {
        int i = base + t + m * 1024;
        if (i < n) {
            unsigned b = (skey[m] & KEYMASK) >> LOCAL_BITS;
            unsigned o = h[b] + lrank[m];
            if (o < WCAP)                                     // overflow guard (+16 sigma)
                pairs[(((b << 3) | xcd) << WSHIFT) + o] = skey[m];
        }
    }
}

// ---- pass 2: unique count, one bucket per block (8 sub-ranges flattened) ----
__global__ void __launch_bounds__(1024, 2)
count_pass(const unsigned* __restrict__ pairs,
           const unsigned* __restrict__ gcur,
           unsigned* __restrict__ ucount) {
    __shared__ unsigned bm[LOCAL_WORDS];      // 32 KB
    __shared__ unsigned wsum[16];
    __shared__ unsigned gb[NXCD + 1];
    int t = threadIdx.x, b = blockIdx.x;
    ((uint4*)bm)[t] = make_uint4(0u, 0u, 0u, 0u);
    ((uint4*)bm)[t + 1024] = make_uint4(0u, 0u, 0u, 0u);
    if (t == 0) {
        unsigned r = 0;
        #pragma unroll
        for (int g = 0; g < NXCD; ++g) {
            gb[g] = r;
            r += min(gcur[((unsigned)b << 3) | g], (unsigned)WCAP);
        }
        gb[NXCD] = r;
    }
    __syncthreads();
    unsigned tot = gb[NXCD];
    for (unsigned p = (unsigned)t; p < tot; p += 1024) {
        unsigned g = 0;
        #pragma unroll
        for (int k = 1; k < NXCD; ++k) g += (p >= gb[k]) ? 1u : 0u;
        unsigned lk = pairs[((((unsigned)b << 3) | g) << WSHIFT) + (p - gb[g])] & LKMASK;
        atomicOr(&bm[lk >> 5], 1u << (lk & 31u));
    }
    __syncthreads();
    unsigned v = 0;
    #pragma unroll
    for (int m = 0; m < 8; ++m) v += __popc(bm[t + 1024 * m]);   // bank = t%32: free
    int ln = t & 63;
    #pragma unroll
    for (int off = 1; off < 64; off <<= 1) v += __shfl_xor(v, off, 64);
    if (ln == 0) wsum[t >> 6] = v;
    __syncthreads();
    if (t == 0) {
        unsigned c = 0;
        #pragma unroll
        for (int m = 0; m < 16; ++m) c += wsum[m];
        ucount[b] = c;
    }
}

// ---- pass 3: emit; coords written by SEQUENTIAL bitmap scan, feats by rank ----
__global__ void __launch_bounds__(1024, 2)
emit_pass(const unsigned* __restrict__ pairs,
          const unsigned* __restrict__ gcur,
          const unsigned* __restrict__ ucount,
          const float* __restrict__ kern,
          float4* __restrict__ out_coords,
          float* __restrict__ out_feats, int n) {
    __shared__ unsigned       bm[LOCAL_WORDS];    // 32 KB
    __shared__ unsigned short pfx[LOCAL_WORDS];   // 16 KB
    __shared__ float          fe[FE_CAP];         // 10 KB
    __shared__ unsigned wsum[16];
    __shared__ unsigned gb[NXCD + 1];
    __shared__ unsigned ubS, totS;
    __shared__ float    kl[8];
    int t = threadIdx.x, b = blockIdx.x;
    if (t < 8) kl[t] = (float)(1 << t) * kern[t];
    ((uint4*)bm)[t] = make_uint4(0u, 0u, 0u, 0u);
    ((uint4*)bm)[t + 1024] = make_uint4(0u, 0u, 0u, 0u);
    for (int i = t; i < FE_CAP; i += 1024) fe[i] = 0.f;
    if (t == 0) {
        unsigned r = 0;
        #pragma unroll
        for (int g = 0; g < NXCD; ++g) {
            gb[g] = r;
            r += min(gcur[((unsigned)b << 3) | g], (unsigned)WCAP);
        }
        gb[NXCD] = r;
    }
    __syncthreads();                               // init + gb before atomicOr build
    unsigned tot = gb[NXCD];
    if (t < 64) {
        // wave 0: exclusive prefix of ucount up to b + grand total
        int ln = t;
        unsigned sum = 0;
        const uint4* uc4 = (const uint4*)ucount;
        #pragma unroll
        for (int q = 0; q < 8; ++q) {
            uint4 u = uc4[ln * 8 + q];
            sum += u.x + u.y + u.z + u.w;
        }
        unsigned incl = sum;
        #pragma unroll
        for (int off = 1; off < 64; off <<= 1) {
            unsigned y = __shfl_up(incl, off, 64);
            if (ln >= off) incl += y;
        }
        if (ln == 63) totS = incl;
        unsigned exclv = incl - sum;
        if (ln == (b >> 5)) {
            unsigned r = exclv;
            int lim = b & 31;
            for (int m = 0; m < lim; ++m) r += ucount[(b & ~31) + m];
            ubS = r;
        }
    } else {
        // waves 1..15: bitmap build over 8 flattened sub-ranges
        for (unsigned p = (unsigned)(t - 64); p < tot; p += 960) {
            unsigned g = 0;
            #pragma unroll
            for (int k = 1; k < NXCD; ++k) g += (p >= gb[k]) ? 1u : 0u;
            unsigned lk = pairs[((((unsigned)b << 3) | g) << WSHIFT) + (p - gb[g])] & LKMASK;
            atomicOr(&bm[lk >> 5], 1u << (lk & 31u));
        }
    }
    __syncthreads();
    // ordered word prefix: thread t owns words [8t, 8t+8)
    uint4 q0 = ((uint4*)bm)[2 * t], q1 = ((uint4*)bm)[2 * t + 1];
    unsigned pc[8] = { (unsigned)__popc(q0.x), (unsigned)__popc(q0.y),
                       (unsigned)__popc(q0.z), (unsigned)__popc(q0.w),
                       (unsigned)__popc(q1.x), (unsigned)__popc(q1.y),
                       (unsigned)__popc(q1.z), (unsigned)__popc(q1.w) };
    unsigned psum = 0;
    #pragma unroll
    for (int m = 0; m < 8; ++m) psum += pc[m];
    unsigned excl, cnt;
    block_scan<16>(psum, wsum, excl, cnt);
    unsigned run = excl;
    #pragma unroll
    for (int m = 0; m < 8; ++m) { pfx[8 * t + m] = (unsigned short)run; run += pc[m]; }
    __syncthreads();
    unsigned ub = ubS;
    // coords: bitmap scan -> fully sequential, coalesced float4 stores
    unsigned wq[8] = { q0.x, q0.y, q0.z, q0.w, q1.x, q1.y, q1.z, q1.w };
    unsigned r2 = excl;
    #pragma unroll
    for (int m = 0; m < 8; ++m) {
        unsigned w = wq[m];
        unsigned hi = ((unsigned)b << LOCAL_BITS) | ((unsigned)(8 * t + m) << 5);
        while (w) {
            unsigned bit = (unsigned)__ffs(w) - 1u;
            w &= w - 1u;
            unsigned key = hi | bit;
            out_coords[ub + r2] = make_float4((float)(key >> 21),
                                              (float)((key >> 14) & 127u),
                                              (float)((key >> 7) & 127u),
                                              (float)(key & 127u));
            ++r2;
        }
    }
    // feats: per point rank -> LDS accumulate
    for (unsigned p = (unsigned)t; p < tot; p += 1024) {
        unsigned g = 0;
        #pragma unroll
        for (int k = 1; k < NXCD; ++k) g += (p >= gb[k]) ? 1u : 0u;
        unsigned pk = pairs[((((unsigned)b << 3) | g) << WSHIFT) + (p - gb[g])];
        unsigned lk = pk & LKMASK;
        unsigned wd = lk >> 5;
        unsigned lr = (unsigned)pfx[wd] + __popc(bm[wd] & ((1u << (lk & 31u)) - 1u));
        atomicAdd(&fe[lr], kl[pk >> 29]);
    }
    __syncthreads();
    for (unsigned i = (unsigned)t; i < cnt; i += 1024)
        out_feats[ub + i] = fe[i];
    // tail fill: rows [totS, n)
    for (unsigned r = totS + (unsigned)(b * 1024 + t); r < (unsigned)n; r += N_BUCKETS * 1024u) {
        out_coords[r] = make_float4(-1.f, -1.f, -1.f, -1.f);
        out_feats[r] = 0.f;
    }
}

extern "C" void kernel_launch(void* const* d_in, const int* in_sizes, int n_in,
                              void* d_out, int out_size, void* d_ws, size_t ws_size,
                              hipStream_t stream) {
    const int4* coords = (const int4*)d_in[0];
    const float* kern  = (const float*)d_in[1];
    int N = in_sizes[0] / 4;

    float* out = (float*)d_out;                   // [4N floats coords][N floats feats]
    float4* out_coords = (float4*)out;
    float* out_feats = out + (size_t)4 * N;

    unsigned* pairs  = (unsigned*)d_ws;                          // 2048*8*512*4B = 32 MB
    unsigned* gcur   = pairs + (size_t)N_BUCKETS * NXCD * WCAP;  // 64 KB
    unsigned* ucount = gcur + (size_t)N_BUCKETS * NXCD;          // 8 KB

    hipMemsetAsync(gcur, 0, (size_t)N_BUCKETS * NXCD * sizeof(unsigned), stream);

    int ntiles = (N + TILE - 1) / TILE;           // 245 for N=4M
    build_pass<<<ntiles, 1024, 0, stream>>>(coords, gcur, pairs, N);
    count_pass<<<N_BUCKETS, 1024, 0, stream>>>(pairs, gcur, ucount);
    emit_pass<<<N_BUCKETS, 1024, 0, stream>>>(pairs, gcur, ucount, kern, out_coords, out_feats, N);
}